// Round 10
// baseline (152742.212 us; speedup 1.0000x reference)
//
#include <hip/hip_runtime.h>
#include <cmath>
#include <vector>

#define B_SZ 64
#define SEQ 512
#define IN_D 512
#define HID 1024
#define MEM_DIM 8
#define ORD 256
#define MFLAT 2048
#define KTOT 3584            // x(512) | h(1024) | m(2048)
#define NH 128               // H-role blocks
#define NM 64                // M-role blocks
#define NBLK (NH + NM)       // 192
#define BAR_STRIDE 16        // u32 stride per slot (64B)

typedef __attribute__((ext_vector_type(8))) short short8v;
typedef __attribute__((ext_vector_type(4))) float f32x4;
typedef unsigned long long u64;

// RNE float->bf16
__device__ __host__ inline unsigned short f2bf(float f) {
  union { float f; unsigned u; } v; v.f = f;
  unsigned r = v.u + 0x7FFF + ((v.u >> 16) & 1);
  return (unsigned short)(r >> 16);
}
__device__ __host__ inline float bf2f(unsigned short h) {
  union { unsigned u; float f; } v; v.u = ((unsigned)h) << 16;
  return v.f;
}

// ---------------- host-side expm (double, scaling & squaring) ----------------
static void matmul_d(const double* A, const double* B, double* C, int n) {
  for (int i = 0; i < n; ++i) {
    double* Ci = C + (size_t)i * n;
    for (int j = 0; j < n; ++j) Ci[j] = 0.0;
    const double* Ai = A + (size_t)i * n;
    for (int k = 0; k < n; ++k) {
      double a = Ai[k];
      const double* Bk = B + (size_t)k * n;
      for (int j = 0; j < n; ++j) Ci[j] += a * Bk[j];
    }
  }
}

static void compute_AB_host(float* AdT, float* Anat, float* Bd) {
  const int q = ORD, n = ORD + 1;
  const double theta = 512.0;
  std::vector<double> M((size_t)n * n, 0.0);
  for (int i = 0; i < q; ++i) {
    double r = (2.0 * i + 1.0) / theta;
    for (int j = 0; j < q; ++j) {
      double v = (i < j) ? -1.0 : ((((i - j) % 2) == 1) ? 1.0 : -1.0);
      M[(size_t)i * n + j] = v * r;
    }
    M[(size_t)i * n + q] = (((i % 2) == 0) ? 1.0 : -1.0) * r;
  }
  double norm = 0.0;
  for (int j = 0; j < n; ++j) {
    double s = 0.0;
    for (int i = 0; i < n; ++i) s += fabs(M[(size_t)i * n + j]);
    if (s > norm) norm = s;
  }
  int s = 0;
  while (norm > 0.25) { norm *= 0.5; ++s; }
  double sc = ldexp(1.0, -s);
  for (size_t i = 0; i < M.size(); ++i) M[i] *= sc;
  std::vector<double> E((size_t)n * n, 0.0), P = M, T((size_t)n * n);
  for (int i = 0; i < n; ++i) E[(size_t)i * n + i] = 1.0;
  for (size_t i = 0; i < M.size(); ++i) E[i] += M[i];
  for (int k = 2; k <= 30; ++k) {
    matmul_d(P.data(), M.data(), T.data(), n);
    double inv = 1.0 / (double)k, mx = 0.0;
    for (size_t i = 0; i < T.size(); ++i) {
      T[i] *= inv;
      double a = fabs(T[i]);
      if (a > mx) mx = a;
    }
    P.swap(T);
    for (size_t i = 0; i < M.size(); ++i) E[i] += P[i];
    if (mx < 1e-19) break;
  }
  for (int it = 0; it < s; ++it) {
    matmul_d(E.data(), E.data(), T.data(), n);
    E.swap(T);
  }
  for (int p = 0; p < q; ++p) {
    for (int o = 0; o < q; ++o) {
      float v = (float)E[(size_t)p * n + o];
      AdT[(size_t)o * q + p] = v;
      Anat[(size_t)p * q + o] = v;
    }
    Bd[p] = (float)E[(size_t)p * n + q];
  }
}

// ---------------- precompute kernels ----------------
__global__ __launch_bounds__(256) void k_wmb(const float* __restrict__ Wm,
                                             const float* __restrict__ Bd,
                                             float* __restrict__ WmB) {
  int i = blockIdx.x;
  int d = threadIdx.x >> 5, l = threadIdx.x & 31;
  const float* wr = Wm + (size_t)i * MFLAT + d * ORD;
  float acc = 0.f;
  #pragma unroll
  for (int j = 0; j < 8; ++j) { int p = l + 32 * j; acc += wr[p] * Bd[p]; }
  for (int off = 16; off; off >>= 1) acc += __shfl_xor(acc, off);
  if (l == 0) WmB[i * 8 + d] = acc;
}

__global__ __launch_bounds__(256) void k_gcat(
    const float* __restrict__ Wx, const float* __restrict__ Wh,
    const float* __restrict__ Wm, const float* __restrict__ Ex,
    const float* __restrict__ Eh, const float* __restrict__ Em,
    const float* __restrict__ Anat, const float* __restrict__ WmB,
    unsigned short* __restrict__ Ghi, unsigned short* __restrict__ Glo) {
  __shared__ float wm[MFLAT];
  __shared__ float wb[8];
  int i = blockIdx.x, tid = threadIdx.x;
  for (int k = tid; k < MFLAT; k += 256) wm[k] = Wm[(size_t)i * MFLAT + k];
  if (tid < 8) wb[tid] = WmB[i * 8 + tid];
  __syncthreads();
  unsigned short* grh = Ghi + (size_t)i * KTOT;
  unsigned short* grl = Glo + (size_t)i * KTOT;
  for (int c = tid; c < KTOT; c += 256) {
    float v;
    if (c < IN_D) {
      v = Wx[(size_t)i * IN_D + c];
      #pragma unroll
      for (int d = 0; d < 8; ++d) v += wb[d] * Ex[(size_t)d * IN_D + c];
    } else if (c < IN_D + HID) {
      int j = c - IN_D;
      v = Wh[(size_t)i * HID + j];
      #pragma unroll
      for (int d = 0; d < 8; ++d) v += wb[d] * Eh[(size_t)d * HID + j];
    } else {
      int cm = c - IN_D - HID;        // (d,o)
      int dd = cm >> 8, o = cm & 255;
      v = 0.f;
      const float* wmd = wm + dd * ORD;
      for (int p = 0; p < ORD; ++p) v += wmd[p] * Anat[(size_t)p * ORD + o];
      #pragma unroll
      for (int d = 0; d < 8; ++d) v += wb[d] * Em[(size_t)d * MFLAT + cm];
    }
    unsigned short hi = f2bf(v);
    grh[c] = hi;
    grl[c] = f2bf(v - bf2f(hi));
  }
}

// ---------------- tree barrier (RELEASE flags + ACQUIRE fence) — round-6 proven ----------------
__device__ inline void grid_barrier(unsigned* __restrict__ arr,
                                    unsigned* __restrict__ go, unsigned ep) {
  __syncthreads();
  if (blockIdx.x == 0) {
    int tid = threadIdx.x;
    if (tid > 0 && tid < NBLK) {
      while (__hip_atomic_load(&arr[tid * BAR_STRIDE], __ATOMIC_RELAXED,
                               __HIP_MEMORY_SCOPE_AGENT) < ep) {}
    }
    __syncthreads();
    if (tid == 0)
      __hip_atomic_store(go, ep, __ATOMIC_RELEASE, __HIP_MEMORY_SCOPE_AGENT);
  } else {
    if (threadIdx.x == 0) {
      __hip_atomic_store(&arr[blockIdx.x * BAR_STRIDE], ep, __ATOMIC_RELEASE,
                         __HIP_MEMORY_SCOPE_AGENT);
      while (__hip_atomic_load(go, __ATOMIC_RELAXED,
                               __HIP_MEMORY_SCOPE_AGENT) < ep) {}
    }
  }
  if (threadIdx.x == 0)
    __builtin_amdgcn_fence(__ATOMIC_ACQUIRE, "agent");
  __syncthreads();
}

// ---------------- REAL kernel: round-6 structure, writes d_out ----------------
__global__ __launch_bounds__(256) void k_persist(
    const float* __restrict__ x, const float* __restrict__ Ex,
    const float* __restrict__ Eh, const float* __restrict__ Em,
    const unsigned short* __restrict__ Ghi, const unsigned short* __restrict__ Glo,
    const float* __restrict__ AdT, const float* __restrict__ Bd,
    unsigned short* __restrict__ sh0, unsigned short* __restrict__ sh1,
    unsigned short* __restrict__ sl0, unsigned short* __restrict__ sl1,
    float* __restrict__ hfp0, float* __restrict__ hfp1,
    float* __restrict__ mfp0, float* __restrict__ mfp1,
    float* __restrict__ out, unsigned* __restrict__ barArr,
    unsigned* __restrict__ barGo) {
  int tid = threadIdx.x;
  unsigned ep = 0;

  if (blockIdx.x < NH) {
    // ================= H role =================
    __shared__ float hx[2][64][4];
    int it = blockIdx.x & 63, bh = blockIdx.x >> 6;
    int w = tid >> 6, lane = tid & 63;
    int tw = w & 1, kh = w >> 1;
    int b0 = bh * 32 + tw * 16;
    int i0 = it * 16;
    size_t aoff = (size_t)(b0 + (lane & 15)) * KTOT + (lane >> 4) * 8;
    const unsigned short* bh_ = Ghi + (size_t)(i0 + (lane & 15)) * KTOT + (lane >> 4) * 8;
    const unsigned short* bl_ = Glo + (size_t)(i0 + (lane & 15)) * KTOT + (lane >> 4) * 8;

    grid_barrier(barArr, barGo, ++ep);

    for (int t = 0; t < SEQ; ++t) {
      const unsigned short* ah_ = ((t & 1) ? sh1 : sh0) + aoff;
      const unsigned short* al_ = ((t & 1) ? sl1 : sl0) + aoff;
      unsigned short* snh = (t & 1) ? sh0 : sh1;
      unsigned short* snl = (t & 1) ? sl0 : sl1;
      float* hn = (t & 1) ? hfp0 : hfp1;

      f32x4 ahh = {0.f,0.f,0.f,0.f}, alh = {0.f,0.f,0.f,0.f}, ahl = {0.f,0.f,0.f,0.f};
      int kbase = kh * 1792;
      #pragma unroll 4
      for (int kk = 0; kk < 56; ++kk) {
        int k = kbase + kk * 32;
        short8v avh = *(const short8v*)(ah_ + k);
        short8v avl = *(const short8v*)(al_ + k);
        short8v bvh = *(const short8v*)(bh_ + k);
        short8v bvl = *(const short8v*)(bl_ + k);
        ahh = __builtin_amdgcn_mfma_f32_16x16x32_bf16(avh, bvh, ahh, 0, 0, 0);
        alh = __builtin_amdgcn_mfma_f32_16x16x32_bf16(avl, bvh, alh, 0, 0, 0);
        ahl = __builtin_amdgcn_mfma_f32_16x16x32_bf16(avh, bvl, ahl, 0, 0, 0);
      }
      f32x4 acc = ahh + alh + ahl;
      if (kh == 1) {
        *(f32x4*)&hx[tw][lane][0] = acc;
      }
      __syncthreads();
      if (kh == 0) {
        f32x4 o4 = *(const f32x4*)&hx[tw][lane][0];
        #pragma unroll
        for (int r = 0; r < 4; ++r) {
          float v = acc[r] + o4[r];
          float hv = tanhf(v);
          int b = b0 + (lane >> 4) * 4 + r;
          int i = i0 + (lane & 15);
          hn[(size_t)b * HID + i] = hv;
          unsigned short hi = f2bf(hv);
          snh[(size_t)b * KTOT + IN_D + i] = hi;
          snl[(size_t)b * KTOT + IN_D + i] = f2bf(hv - bf2f(hi));
          __builtin_nontemporal_store(hv, &out[((size_t)b * SEQ + t) * HID + i]);
        }
      }
      grid_barrier(barArr, barGo, ++ep);
    }
  } else {
    // ================= M role =================
    __shared__ float sst[KTOT];
    __shared__ float part[4][MFLAT];
    __shared__ float ush[8];
    int b = blockIdx.x - NH;
    int du = tid >> 5, lu = tid & 31;
    const float* exr = Ex + (size_t)du * IN_D;
    const float* ehr = Eh + (size_t)du * HID;
    const float* emr = Em + (size_t)du * MFLAT;
    int os = tid >> 6;
    int p0 = (tid & 63) * 4;
    int dp0 = tid * 8;
    int dr = tid >> 5;
    float bdv[8];
    #pragma unroll
    for (int j = 0; j < 8; ++j) bdv[j] = Bd[(dp0 & 255) + j];

    {
      const float* xr = x + (size_t)b * SEQ * IN_D;
      for (int k = tid; k < IN_D; k += 256) {
        float xv = xr[k];
        unsigned short hi = f2bf(xv);
        sh0[(size_t)b * KTOT + k] = hi;
        sl0[(size_t)b * KTOT + k] = f2bf(xv - bf2f(hi));
      }
    }
    grid_barrier(barArr, barGo, ++ep);

    for (int t = 0; t < SEQ; ++t) {
      const float* hc = (t & 1) ? hfp1 : hfp0;
      const float* mc = (t & 1) ? mfp1 : mfp0;
      float* mn = (t & 1) ? mfp0 : mfp1;
      unsigned short* snh = (t & 1) ? sh0 : sh1;
      unsigned short* snl = (t & 1) ? sl0 : sl1;

      const float* xrow = x + ((size_t)b * SEQ + t) * IN_D;
      #pragma unroll
      for (int j = 0; j < 14; ++j) {
        int k = tid + 256 * j;
        float v;
        if (k < IN_D) v = xrow[k];
        else if (k < IN_D + HID) v = hc[(size_t)b * HID + (k - IN_D)];
        else v = mc[(size_t)b * MFLAT + (k - IN_D - HID)];
        sst[k] = v;
      }
      __syncthreads();

      float ua = 0.f;
      #pragma unroll 4
      for (int j = 0; j < 16; ++j) { int k = lu + 32 * j; ua += exr[k] * sst[k]; }
      #pragma unroll 4
      for (int j = 0; j < 32; ++j) { int k = lu + 32 * j; ua += ehr[k] * sst[IN_D + k]; }
      #pragma unroll 4
      for (int j = 0; j < 64; ++j) { int k = lu + 32 * j; ua += emr[k] * sst[IN_D + HID + k]; }
      #pragma unroll
      for (int off = 16; off; off >>= 1) ua += __shfl_xor(ua, off);
      if (lu == 0) ush[du] = ua;
      __syncthreads();

      float acc[8][4];
      #pragma unroll
      for (int d = 0; d < 8; ++d)
        acc[d][0] = acc[d][1] = acc[d][2] = acc[d][3] = 0.f;
      const float* mbase = sst + IN_D + HID;
      #pragma unroll 4
      for (int oo = 0; oo < 64; ++oo) {
        int o = os * 64 + oo;
        float4 q = *(const float4*)(AdT + (size_t)o * ORD + p0);
        #pragma unroll
        for (int d = 0; d < 8; ++d) {
          float mv = mbase[d * ORD + o];
          acc[d][0] = fmaf(q.x, mv, acc[d][0]);
          acc[d][1] = fmaf(q.y, mv, acc[d][1]);
          acc[d][2] = fmaf(q.z, mv, acc[d][2]);
          acc[d][3] = fmaf(q.w, mv, acc[d][3]);
        }
      }
      #pragma unroll
      for (int d = 0; d < 8; ++d)
        *(float4*)&part[os][d * ORD + p0] =
            make_float4(acc[d][0], acc[d][1], acc[d][2], acc[d][3]);
      __syncthreads();

      float r[8];
      float uv = ush[dr];
      #pragma unroll
      for (int j = 0; j < 8; ++j) r[j] = bdv[j] * uv;
      #pragma unroll
      for (int s = 0; s < 4; ++s) {
        float4 v0 = *(const float4*)&part[s][dp0];
        float4 v1 = *(const float4*)&part[s][dp0 + 4];
        r[0] += v0.x; r[1] += v0.y; r[2] += v0.z; r[3] += v0.w;
        r[4] += v1.x; r[5] += v1.y; r[6] += v1.z; r[7] += v1.w;
      }
      float4* mo4 = (float4*)(mn + (size_t)b * MFLAT + dp0);
      mo4[0] = make_float4(r[0], r[1], r[2], r[3]);
      mo4[1] = make_float4(r[4], r[5], r[6], r[7]);
      unsigned short ph[8], pl[8];
      #pragma unroll
      for (int j = 0; j < 8; ++j) {
        ph[j] = f2bf(r[j]);
        pl[j] = f2bf(r[j] - bf2f(ph[j]));
      }
      size_t moff = (size_t)b * KTOT + IN_D + HID + dp0;
      *(short8v*)(snh + moff) = *(short8v*)ph;
      *(short8v*)(snl + moff) = *(short8v*)pl;

      if (t + 1 < SEQ) {
        const float* xn = x + ((size_t)b * SEQ + t + 1) * IN_D;
        for (int k = tid; k < IN_D; k += 256) {
          float xv = xn[k];
          unsigned short hi = f2bf(xv);
          snh[(size_t)b * KTOT + k] = hi;
          snl[(size_t)b * KTOT + k] = f2bf(xv - bf2f(hi));
        }
      }
      __syncthreads();
      grid_barrier(barArr, barGo, ++ep);
    }
  }
}

// ---------------- PROBE 1: barrier-only, 8x amplified (4097 epochs) ----------------
__global__ __launch_bounds__(256) void k_bar8(unsigned* __restrict__ arr,
                                              unsigned* __restrict__ go) {
  unsigned ep = 0;
  for (int i = 0; i < 8 * SEQ + 1; ++i)
    grid_barrier(arr, go, ++ep);
}

// ---------------- PROBE 2: compute-only (no fences/atomics), 8 reps ----------------
__global__ __launch_bounds__(256) void k_comp8(
    const float* __restrict__ x, const float* __restrict__ Ex,
    const float* __restrict__ Eh, const float* __restrict__ Em,
    const unsigned short* __restrict__ Ghi, const unsigned short* __restrict__ Glo,
    const float* __restrict__ AdT, const float* __restrict__ Bd,
    unsigned short* __restrict__ sh0, unsigned short* __restrict__ sh1,
    unsigned short* __restrict__ sl0, unsigned short* __restrict__ sl1,
    float* __restrict__ hfp0, float* __restrict__ hfp1,
    float* __restrict__ mfp0, float* __restrict__ mfp1,
    float* __restrict__ dummy) {
  int tid = threadIdx.x;

  if (blockIdx.x < NH) {
    __shared__ float hx[2][64][4];
    int it = blockIdx.x & 63, bh = blockIdx.x >> 6;
    int w = tid >> 6, lane = tid & 63;
    int tw = w & 1, kh = w >> 1;
    int b0 = bh * 32 + tw * 16;
    int i0 = it * 16;
    size_t aoff = (size_t)(b0 + (lane & 15)) * KTOT + (lane >> 4) * 8;
    const unsigned short* bh_ = Ghi + (size_t)(i0 + (lane & 15)) * KTOT + (lane >> 4) * 8;
    const unsigned short* bl_ = Glo + (size_t)(i0 + (lane & 15)) * KTOT + (lane >> 4) * 8;

    for (int rep = 0; rep < 8; ++rep)
    for (int t = 0; t < SEQ; ++t) {
      const unsigned short* ah_ = ((t & 1) ? sh1 : sh0) + aoff;
      const unsigned short* al_ = ((t & 1) ? sl1 : sl0) + aoff;
      unsigned short* snh = (t & 1) ? sh0 : sh1;
      unsigned short* snl = (t & 1) ? sl0 : sl1;
      float* hn = (t & 1) ? hfp0 : hfp1;

      f32x4 ahh = {0.f,0.f,0.f,0.f}, alh = {0.f,0.f,0.f,0.f}, ahl = {0.f,0.f,0.f,0.f};
      int kbase = kh * 1792;
      #pragma unroll 4
      for (int kk = 0; kk < 56; ++kk) {
        int k = kbase + kk * 32;
        short8v avh = *(const short8v*)(ah_ + k);
        short8v avl = *(const short8v*)(al_ + k);
        short8v bvh = *(const short8v*)(bh_ + k);
        short8v bvl = *(const short8v*)(bl_ + k);
        ahh = __builtin_amdgcn_mfma_f32_16x16x32_bf16(avh, bvh, ahh, 0, 0, 0);
        alh = __builtin_amdgcn_mfma_f32_16x16x32_bf16(avl, bvh, alh, 0, 0, 0);
        ahl = __builtin_amdgcn_mfma_f32_16x16x32_bf16(avh, bvl, ahl, 0, 0, 0);
      }
      f32x4 acc = ahh + alh + ahl;
      if (kh == 1) {
        *(f32x4*)&hx[tw][lane][0] = acc;
      }
      __syncthreads();
      if (kh == 0) {
        f32x4 o4 = *(const f32x4*)&hx[tw][lane][0];
        #pragma unroll
        for (int r = 0; r < 4; ++r) {
          float v = acc[r] + o4[r];
          float hv = tanhf(v);
          int b = b0 + (lane >> 4) * 4 + r;
          int i = i0 + (lane & 15);
          hn[(size_t)b * HID + i] = hv;
          unsigned short hi = f2bf(hv);
          snh[(size_t)b * KTOT + IN_D + i] = hi;
          snl[(size_t)b * KTOT + IN_D + i] = f2bf(hv - bf2f(hi));
          size_t oidx = ((size_t)b * SEQ + t) * HID + i;
          __builtin_nontemporal_store(hv, &dummy[oidx & 0xFFFF]);
        }
      }
      __syncthreads();
    }
  } else {
    __shared__ float sst[KTOT];
    __shared__ float part[4][MFLAT];
    __shared__ float ush[8];
    int b = blockIdx.x - NH;
    int du = tid >> 5, lu = tid & 31;
    const float* exr = Ex + (size_t)du * IN_D;
    const float* ehr = Eh + (size_t)du * HID;
    const float* emr = Em + (size_t)du * MFLAT;
    int os = tid >> 6;
    int p0 = (tid & 63) * 4;
    int dp0 = tid * 8;
    int dr = tid >> 5;
    float bdv[8];
    #pragma unroll
    for (int j = 0; j < 8; ++j) bdv[j] = Bd[(dp0 & 255) + j];

    for (int rep = 0; rep < 8; ++rep)
    for (int t = 0; t < SEQ; ++t) {
      const float* hc = (t & 1) ? hfp1 : hfp0;
      const float* mc = (t & 1) ? mfp1 : mfp0;
      float* mn = (t & 1) ? mfp0 : mfp1;
      unsigned short* snh = (t & 1) ? sh0 : sh1;
      unsigned short* snl = (t & 1) ? sl0 : sl1;

      const float* xrow = x + ((size_t)b * SEQ + t) * IN_D;
      #pragma unroll
      for (int j = 0; j < 14; ++j) {
        int k = tid + 256 * j;
        float v;
        if (k < IN_D) v = xrow[k];
        else if (k < IN_D + HID) v = hc[(size_t)b * HID + (k - IN_D)];
        else v = mc[(size_t)b * MFLAT + (k - IN_D - HID)];
        sst[k] = v;
      }
      __syncthreads();

      float ua = 0.f;
      #pragma unroll 4
      for (int j = 0; j < 16; ++j) { int k = lu + 32 * j; ua += exr[k] * sst[k]; }
      #pragma unroll 4
      for (int j = 0; j < 32; ++j) { int k = lu + 32 * j; ua += ehr[k] * sst[IN_D + k]; }
      #pragma unroll 4
      for (int j = 0; j < 64; ++j) { int k = lu + 32 * j; ua += emr[k] * sst[IN_D + HID + k]; }
      #pragma unroll
      for (int off = 16; off; off >>= 1) ua += __shfl_xor(ua, off);
      if (lu == 0) ush[du] = ua;
      __syncthreads();

      float acc[8][4];
      #pragma unroll
      for (int d = 0; d < 8; ++d)
        acc[d][0] = acc[d][1] = acc[d][2] = acc[d][3] = 0.f;
      const float* mbase = sst + IN_D + HID;
      #pragma unroll 4
      for (int oo = 0; oo < 64; ++oo) {
        int o = os * 64 + oo;
        float4 q = *(const float4*)(AdT + (size_t)o * ORD + p0);
        #pragma unroll
        for (int d = 0; d < 8; ++d) {
          float mv = mbase[d * ORD + o];
          acc[d][0] = fmaf(q.x, mv, acc[d][0]);
          acc[d][1] = fmaf(q.y, mv, acc[d][1]);
          acc[d][2] = fmaf(q.z, mv, acc[d][2]);
          acc[d][3] = fmaf(q.w, mv, acc[d][3]);
        }
      }
      #pragma unroll
      for (int d = 0; d < 8; ++d)
        *(float4*)&part[os][d * ORD + p0] =
            make_float4(acc[d][0], acc[d][1], acc[d][2], acc[d][3]);
      __syncthreads();

      float r[8];
      float uv = ush[dr];
      #pragma unroll
      for (int j = 0; j < 8; ++j) r[j] = bdv[j] * uv;
      #pragma unroll
      for (int s = 0; s < 4; ++s) {
        float4 v0 = *(const float4*)&part[s][dp0];
        float4 v1 = *(const float4*)&part[s][dp0 + 4];
        r[0] += v0.x; r[1] += v0.y; r[2] += v0.z; r[3] += v0.w;
        r[4] += v1.x; r[5] += v1.y; r[6] += v1.z; r[7] += v1.w;
      }
      float4* mo4 = (float4*)(mn + (size_t)b * MFLAT + dp0);
      mo4[0] = make_float4(r[0], r[1], r[2], r[3]);
      mo4[1] = make_float4(r[4], r[5], r[6], r[7]);
      unsigned short ph[8], pl[8];
      #pragma unroll
      for (int j = 0; j < 8; ++j) {
        ph[j] = f2bf(r[j]);
        pl[j] = f2bf(r[j] - bf2f(ph[j]));
      }
      size_t moff = (size_t)b * KTOT + IN_D + HID + dp0;
      *(short8v*)(snh + moff) = *(short8v*)ph;
      *(short8v*)(snl + moff) = *(short8v*)pl;

      if (t + 1 < SEQ) {
        const float* xn = x + ((size_t)b * SEQ + t + 1) * IN_D;
        for (int k = tid; k < IN_D; k += 256) {
          float xv = xn[k];
          unsigned short hi = f2bf(xv);
          snh[(size_t)b * KTOT + k] = hi;
          snl[(size_t)b * KTOT + k] = f2bf(xv - bf2f(hi));
        }
      }
      __syncthreads();
      __syncthreads();
    }
  }
}

// ---------------- launch ----------------
extern "C" void kernel_launch(void* const* d_in, const int* in_sizes, int n_in,
                              void* d_out, int out_size, void* d_ws, size_t ws_size,
                              hipStream_t stream) {
  const float* x  = (const float*)d_in[0];
  const float* Ex = (const float*)d_in[1];
  const float* Eh = (const float*)d_in[2];
  const float* Em = (const float*)d_in[3];
  const float* Wx = (const float*)d_in[4];
  const float* Wh = (const float*)d_in[5];
  const float* Wm = (const float*)d_in[6];
  float* out = (float*)d_out;
  float* ws = (float*)d_ws;

  float* dAnat = ws;                         // 65536 f (also k_comp8 dummy-out)
  float* dAdT  = dAnat + 65536;              // 65536 f
  float* dBd   = dAdT + 65536;               // 512 f
  float* dWmB  = dBd + 512;                  // 8192 f
  unsigned short* dGhi = (unsigned short*)(dWmB + 8192);      // 1024*3584 ush
  unsigned short* dGlo = dGhi + (size_t)HID * KTOT;
  unsigned short* sh0  = dGlo + (size_t)HID * KTOT;           // 64*3584 ush each
  unsigned short* sh1  = sh0 + (size_t)B_SZ * KTOT;
  unsigned short* sl0  = sh1 + (size_t)B_SZ * KTOT;
  unsigned short* sl1  = sl0 + (size_t)B_SZ * KTOT;
  float* hfp0 = (float*)(sl1 + (size_t)B_SZ * KTOT);
  float* hfp1 = hfp0 + B_SZ * HID;
  float* mfp0 = hfp1 + B_SZ * HID;
  float* mfp1 = mfp0 + B_SZ * MFLAT;
  unsigned* barArr  = (unsigned*)(mfp1 + B_SZ * MFLAT);       // NBLK*16
  unsigned* barGo   = barArr + NBLK * BAR_STRIDE;             // 16
  unsigned* barArrB = barGo + BAR_STRIDE;                     // NBLK*16 (bar8 probe)
  unsigned* barGoB  = barArrB + NBLK * BAR_STRIDE;            // 16

  static float h_AdT[ORD * ORD];
  static float h_Anat[ORD * ORD];
  static float h_Bd[ORD];
  compute_AB_host(h_AdT, h_Anat, h_Bd);
  hipMemcpyAsync(dAdT,  h_AdT,  sizeof(h_AdT),  hipMemcpyHostToDevice, stream);
  hipMemcpyAsync(dAnat, h_Anat, sizeof(h_Anat), hipMemcpyHostToDevice, stream);
  hipMemcpyAsync(dBd,   h_Bd,   sizeof(h_Bd),   hipMemcpyHostToDevice, stream);

  hipMemsetAsync(sh0, 0, (size_t)B_SZ * KTOT * sizeof(unsigned short), stream);
  hipMemsetAsync(sl0, 0, (size_t)B_SZ * KTOT * sizeof(unsigned short), stream);
  hipMemsetAsync(hfp0, 0, (size_t)B_SZ * HID * sizeof(float), stream);
  hipMemsetAsync(mfp0, 0, (size_t)B_SZ * MFLAT * sizeof(float), stream);
  hipMemsetAsync(barArr, 0,
                 (size_t)(NBLK * BAR_STRIDE + BAR_STRIDE) * 2 * sizeof(unsigned), stream);

  k_wmb<<<dim3(HID), dim3(256), 0, stream>>>(Wm, dBd, dWmB);
  k_gcat<<<dim3(HID), dim3(256), 0, stream>>>(Wx, Wh, Wm, Ex, Eh, Em, dAnat, dWmB, dGhi, dGlo);

  // real run (round-6 structure, proven 19.4 ms)
  k_persist<<<dim3(NBLK), dim3(256), 0, stream>>>(
      x, Ex, Eh, Em, dGhi, dGlo, dAdT, dBd, sh0, sh1, sl0, sl1,
      hfp0, hfp1, mfp0, mfp1, out, barArr, barGo);
  // probe 1: barrier-only x8
  k_bar8<<<dim3(NBLK), dim3(256), 0, stream>>>(barArrB, barGoB);
  // probe 2: compute-only x8 (no fences), writes masked into dAnat
  k_comp8<<<dim3(NBLK), dim3(256), 0, stream>>>(
      x, Ex, Eh, Em, dGhi, dGlo, dAdT, dBd, sh0, sh1, sl0, sl1,
      hfp0, hfp1, mfp0, mfp1, dAnat);
}

// Round 12
// 59484.901 us; speedup vs baseline: 2.5677x; 2.5677x over previous
//
#include <hip/hip_runtime.h>
#include <cmath>
#include <vector>

#define B_SZ 64
#define SEQ 512
#define IN_D 512
#define HID 1024
#define MEM_DIM 8
#define ORD 256
#define MFLAT 2048
#define KTOT 3584            // x(512) | h(1024) | m(2048)
#define NH 128               // H-role blocks: 8 slices x 4 isub x 4 bq
#define NM 64                // M-role blocks
#define NBLK (NH + NM)       // 192
#define BAR_STRIDE 16        // u32 stride per slot (64B)

typedef __attribute__((ext_vector_type(8))) short short8v;
typedef __attribute__((ext_vector_type(4))) float f32x4;
typedef unsigned long long u64;

// RNE float->bf16
__device__ __host__ inline unsigned short f2bf(float f) {
  union { float f; unsigned u; } v; v.f = f;
  unsigned r = v.u + 0x7FFF + ((v.u >> 16) & 1);
  return (unsigned short)(r >> 16);
}
__device__ __host__ inline float bf2f(unsigned short h) {
  union { unsigned u; float f; } v; v.u = ((unsigned)h) << 16;
  return v.f;
}

// ---------------- host-side expm (double, scaling & squaring) ----------------
static void matmul_d(const double* A, const double* B, double* C, int n) {
  for (int i = 0; i < n; ++i) {
    double* Ci = C + (size_t)i * n;
    for (int j = 0; j < n; ++j) Ci[j] = 0.0;
    const double* Ai = A + (size_t)i * n;
    for (int k = 0; k < n; ++k) {
      double a = Ai[k];
      const double* Bk = B + (size_t)k * n;
      for (int j = 0; j < n; ++j) Ci[j] += a * Bk[j];
    }
  }
}

static void compute_AB_host(float* AdT, float* Anat, float* Bd) {
  const int q = ORD, n = ORD + 1;
  const double theta = 512.0;
  std::vector<double> M((size_t)n * n, 0.0);
  for (int i = 0; i < q; ++i) {
    double r = (2.0 * i + 1.0) / theta;
    for (int j = 0; j < q; ++j) {
      double v = (i < j) ? -1.0 : ((((i - j) % 2) == 1) ? 1.0 : -1.0);
      M[(size_t)i * n + j] = v * r;
    }
    M[(size_t)i * n + q] = (((i % 2) == 0) ? 1.0 : -1.0) * r;
  }
  double norm = 0.0;
  for (int j = 0; j < n; ++j) {
    double s = 0.0;
    for (int i = 0; i < n; ++i) s += fabs(M[(size_t)i * n + j]);
    if (s > norm) norm = s;
  }
  int s = 0;
  while (norm > 0.25) { norm *= 0.5; ++s; }
  double sc = ldexp(1.0, -s);
  for (size_t i = 0; i < M.size(); ++i) M[i] *= sc;
  std::vector<double> E((size_t)n * n, 0.0), P = M, T((size_t)n * n);
  for (int i = 0; i < n; ++i) E[(size_t)i * n + i] = 1.0;
  for (size_t i = 0; i < M.size(); ++i) E[i] += M[i];
  for (int k = 2; k <= 30; ++k) {
    matmul_d(P.data(), M.data(), T.data(), n);
    double inv = 1.0 / (double)k, mx = 0.0;
    for (size_t i = 0; i < T.size(); ++i) {
      T[i] *= inv;
      double a = fabs(T[i]);
      if (a > mx) mx = a;
    }
    P.swap(T);
    for (size_t i = 0; i < M.size(); ++i) E[i] += P[i];
    if (mx < 1e-19) break;
  }
  for (int it = 0; it < s; ++it) {
    matmul_d(E.data(), E.data(), T.data(), n);
    E.swap(T);
  }
  for (int p = 0; p < q; ++p) {
    for (int o = 0; o < q; ++o) {
      float v = (float)E[(size_t)p * n + o];
      AdT[(size_t)o * q + p] = v;
      Anat[(size_t)p * q + o] = v;
    }
    Bd[p] = (float)E[(size_t)p * n + q];
  }
}

// ---------------- precompute kernels ----------------
__global__ __launch_bounds__(256) void k_wmb(const float* __restrict__ Wm,
                                             const float* __restrict__ Bd,
                                             float* __restrict__ WmB) {
  int i = blockIdx.x;
  int d = threadIdx.x >> 5, l = threadIdx.x & 31;
  const float* wr = Wm + (size_t)i * MFLAT + d * ORD;
  float acc = 0.f;
  #pragma unroll
  for (int j = 0; j < 8; ++j) { int p = l + 32 * j; acc += wr[p] * Bd[p]; }
  for (int off = 16; off; off >>= 1) acc += __shfl_xor(acc, off);
  if (l == 0) WmB[i * 8 + d] = acc;
}

__global__ __launch_bounds__(256) void k_gcat(
    const float* __restrict__ Wx, const float* __restrict__ Wh,
    const float* __restrict__ Wm, const float* __restrict__ Ex,
    const float* __restrict__ Eh, const float* __restrict__ Em,
    const float* __restrict__ Anat, const float* __restrict__ WmB,
    unsigned short* __restrict__ Ghi, unsigned short* __restrict__ Glo) {
  __shared__ float wm[MFLAT];
  __shared__ float wb[8];
  int i = blockIdx.x, tid = threadIdx.x;
  for (int k = tid; k < MFLAT; k += 256) wm[k] = Wm[(size_t)i * MFLAT + k];
  if (tid < 8) wb[tid] = WmB[i * 8 + tid];
  __syncthreads();
  unsigned short* grh = Ghi + (size_t)i * KTOT;
  unsigned short* grl = Glo + (size_t)i * KTOT;
  for (int c = tid; c < KTOT; c += 256) {
    float v;
    if (c < IN_D) {
      v = Wx[(size_t)i * IN_D + c];
      #pragma unroll
      for (int d = 0; d < 8; ++d) v += wb[d] * Ex[(size_t)d * IN_D + c];
    } else if (c < IN_D + HID) {
      int j = c - IN_D;
      v = Wh[(size_t)i * HID + j];
      #pragma unroll
      for (int d = 0; d < 8; ++d) v += wb[d] * Eh[(size_t)d * HID + j];
    } else {
      int cm = c - IN_D - HID;        // (d,o)
      int dd = cm >> 8, o = cm & 255;
      v = 0.f;
      const float* wmd = wm + dd * ORD;
      for (int p = 0; p < ORD; ++p) v += wmd[p] * Anat[(size_t)p * ORD + o];
      #pragma unroll
      for (int d = 0; d < 8; ++d) v += wb[d] * Em[(size_t)d * MFLAT + cm];
    }
    unsigned short hi = f2bf(v);
    grh[c] = hi;
    grl[c] = f2bf(v - bf2f(hi));
  }
}

// ---------------- tree barrier (RELEASE flags + ACQUIRE fence) — proven ----------------
__device__ inline void grid_barrier(unsigned* __restrict__ arr,
                                    unsigned* __restrict__ go, unsigned ep) {
  __syncthreads();
  if (blockIdx.x == 0) {
    int tid = threadIdx.x;
    if (tid > 0 && tid < NBLK) {
      while (__hip_atomic_load(&arr[tid * BAR_STRIDE], __ATOMIC_RELAXED,
                               __HIP_MEMORY_SCOPE_AGENT) < ep) {}
    }
    __syncthreads();
    if (tid == 0)
      __hip_atomic_store(go, ep, __ATOMIC_RELEASE, __HIP_MEMORY_SCOPE_AGENT);
  } else {
    if (threadIdx.x == 0) {
      __hip_atomic_store(&arr[blockIdx.x * BAR_STRIDE], ep, __ATOMIC_RELEASE,
                         __HIP_MEMORY_SCOPE_AGENT);
      while (__hip_atomic_load(go, __ATOMIC_RELAXED,
                               __HIP_MEMORY_SCOPE_AGENT) < ep) {}
    }
  }
  if (threadIdx.x == 0)
    __builtin_amdgcn_fence(__ATOMIC_ACQUIRE, "agent");
  __syncthreads();
}

// ---------------- persistent kernel ----------------
// H blocks [0,128): blk = s + 8*(isub + 4*bq). Slice s (128 i-cols) is touched ONLY
// by blocks ≡ s (mod 8) -> all on XCD s -> G slice (1.84 MB) stays L2-resident.
// Tile 16b x 32i; waves (tw = i-half, kh = K-half) — inner loop VERBATIM round-6/9.
// M blocks [128,192): batch b (round-6 proven path, unchanged).
__global__ __launch_bounds__(256) void k_persist(
    const float* __restrict__ x, const float* __restrict__ Ex,
    const float* __restrict__ Eh, const float* __restrict__ Em,
    const unsigned short* __restrict__ Ghi, const unsigned short* __restrict__ Glo,
    const float* __restrict__ AdT, const float* __restrict__ Bd,
    unsigned short* __restrict__ sh0, unsigned short* __restrict__ sh1,
    unsigned short* __restrict__ sl0, unsigned short* __restrict__ sl1,
    float* __restrict__ hfp0, float* __restrict__ hfp1,
    float* __restrict__ mfp0, float* __restrict__ mfp1,
    float* __restrict__ out, unsigned* __restrict__ barArr,
    unsigned* __restrict__ barGo) {
  int tid = threadIdx.x;
  unsigned ep = 0;

  if (blockIdx.x < NH) {
    // ================= H role =================
    __shared__ float hx[2][64][4];
    int s = blockIdx.x & 7, sub = blockIdx.x >> 3;    // slice, sub-tile
    int isub = sub & 3, bq = sub >> 2;
    int w = tid >> 6, lane = tid & 63;
    int tw = w & 1, kh = w >> 1;
    int b0 = bq * 16;
    int i0 = s * 128 + isub * 32 + tw * 16;
    size_t aoff = (size_t)(b0 + (lane & 15)) * KTOT + (lane >> 4) * 8;
    const unsigned short* bh_ = Ghi + (size_t)(i0 + (lane & 15)) * KTOT + (lane >> 4) * 8;
    const unsigned short* bl_ = Glo + (size_t)(i0 + (lane & 15)) * KTOT + (lane >> 4) * 8;

    grid_barrier(barArr, barGo, ++ep);

    for (int t = 0; t < SEQ; ++t) {
      const unsigned short* ah_ = ((t & 1) ? sh1 : sh0) + aoff;
      const unsigned short* al_ = ((t & 1) ? sl1 : sl0) + aoff;
      unsigned short* snh = (t & 1) ? sh0 : sh1;
      unsigned short* snl = (t & 1) ? sl0 : sl1;
      float* hn = (t & 1) ? hfp0 : hfp1;

      f32x4 ahh = {0.f,0.f,0.f,0.f}, alh = {0.f,0.f,0.f,0.f}, ahl = {0.f,0.f,0.f,0.f};
      int kbase = kh * 1792;
      #pragma unroll 4
      for (int kk = 0; kk < 56; ++kk) {
        int k = kbase + kk * 32;
        short8v avh = *(const short8v*)(ah_ + k);
        short8v avl = *(const short8v*)(al_ + k);
        short8v bvh = *(const short8v*)(bh_ + k);
        short8v bvl = *(const short8v*)(bl_ + k);
        ahh = __builtin_amdgcn_mfma_f32_16x16x32_bf16(avh, bvh, ahh, 0, 0, 0);
        alh = __builtin_amdgcn_mfma_f32_16x16x32_bf16(avl, bvh, alh, 0, 0, 0);
        ahl = __builtin_amdgcn_mfma_f32_16x16x32_bf16(avh, bvl, ahl, 0, 0, 0);
      }
      f32x4 acc = ahh + alh + ahl;
      if (kh == 1) {
        *(f32x4*)&hx[tw][lane][0] = acc;
      }
      __syncthreads();
      if (kh == 0) {
        f32x4 o4 = *(const f32x4*)&hx[tw][lane][0];
        #pragma unroll
        for (int r = 0; r < 4; ++r) {
          float v = acc[r] + o4[r];
          float hv = tanhf(v);
          int b = b0 + (lane >> 4) * 4 + r;
          int i = i0 + (lane & 15);
          hn[(size_t)b * HID + i] = hv;
          unsigned short hi = f2bf(hv);
          snh[(size_t)b * KTOT + IN_D + i] = hi;
          snl[(size_t)b * KTOT + IN_D + i] = f2bf(hv - bf2f(hi));
          __builtin_nontemporal_store(hv, &out[((size_t)b * SEQ + t) * HID + i]);
        }
      }
      grid_barrier(barArr, barGo, ++ep);
    }
  } else {
    // ================= M role (unchanged, proven) =================
    __shared__ float sst[KTOT];
    __shared__ float mpart[4][MFLAT];
    __shared__ float ush[8];
    int b = blockIdx.x - NH;
    int du = tid >> 5, lu = tid & 31;
    const float* exr = Ex + (size_t)du * IN_D;
    const float* ehr = Eh + (size_t)du * HID;
    const float* emr = Em + (size_t)du * MFLAT;
    int os = tid >> 6;
    int p0 = (tid & 63) * 4;
    int dp0 = tid * 8;
    int dr = tid >> 5;
    float bdv[8];
    #pragma unroll
    for (int j = 0; j < 8; ++j) bdv[j] = Bd[(dp0 & 255) + j];

    {
      const float* xr = x + (size_t)b * SEQ * IN_D;
      for (int k = tid; k < IN_D; k += 256) {
        float xv = xr[k];
        unsigned short hi = f2bf(xv);
        sh0[(size_t)b * KTOT + k] = hi;
        sl0[(size_t)b * KTOT + k] = f2bf(xv - bf2f(hi));
      }
    }
    grid_barrier(barArr, barGo, ++ep);

    for (int t = 0; t < SEQ; ++t) {
      const float* hc = (t & 1) ? hfp1 : hfp0;
      const float* mc = (t & 1) ? mfp1 : mfp0;
      float* mn = (t & 1) ? mfp0 : mfp1;
      unsigned short* snh = (t & 1) ? sh0 : sh1;
      unsigned short* snl = (t & 1) ? sl0 : sl1;

      const float* xrow = x + ((size_t)b * SEQ + t) * IN_D;
      #pragma unroll
      for (int j = 0; j < 14; ++j) {
        int k = tid + 256 * j;
        float v;
        if (k < IN_D) v = xrow[k];
        else if (k < IN_D + HID) v = hc[(size_t)b * HID + (k - IN_D)];
        else v = mc[(size_t)b * MFLAT + (k - IN_D - HID)];
        sst[k] = v;
      }
      __syncthreads();

      float ua = 0.f;
      #pragma unroll 4
      for (int j = 0; j < 16; ++j) { int k = lu + 32 * j; ua += exr[k] * sst[k]; }
      #pragma unroll 4
      for (int j = 0; j < 32; ++j) { int k = lu + 32 * j; ua += ehr[k] * sst[IN_D + k]; }
      #pragma unroll 4
      for (int j = 0; j < 64; ++j) { int k = lu + 32 * j; ua += emr[k] * sst[IN_D + HID + k]; }
      #pragma unroll
      for (int off = 16; off; off >>= 1) ua += __shfl_xor(ua, off);
      if (lu == 0) ush[du] = ua;
      __syncthreads();

      float acc[8][4];
      #pragma unroll
      for (int d = 0; d < 8; ++d)
        acc[d][0] = acc[d][1] = acc[d][2] = acc[d][3] = 0.f;
      const float* mbase = sst + IN_D + HID;
      #pragma unroll 4
      for (int oo = 0; oo < 64; ++oo) {
        int o = os * 64 + oo;
        float4 qv = *(const float4*)(AdT + (size_t)o * ORD + p0);
        #pragma unroll
        for (int d = 0; d < 8; ++d) {
          float mv = mbase[d * ORD + o];
          acc[d][0] = fmaf(qv.x, mv, acc[d][0]);
          acc[d][1] = fmaf(qv.y, mv, acc[d][1]);
          acc[d][2] = fmaf(qv.z, mv, acc[d][2]);
          acc[d][3] = fmaf(qv.w, mv, acc[d][3]);
        }
      }
      #pragma unroll
      for (int d = 0; d < 8; ++d)
        *(float4*)&mpart[os][d * ORD + p0] =
            make_float4(acc[d][0], acc[d][1], acc[d][2], acc[d][3]);
      __syncthreads();

      float r[8];
      float uv = ush[dr];
      #pragma unroll
      for (int j = 0; j < 8; ++j) r[j] = bdv[j] * uv;
      #pragma unroll
      for (int sI = 0; sI < 4; ++sI) {
        float4 v0 = *(const float4*)&mpart[sI][dp0];
        float4 v1 = *(const float4*)&mpart[sI][dp0 + 4];
        r[0] += v0.x; r[1] += v0.y; r[2] += v0.z; r[3] += v0.w;
        r[4] += v1.x; r[5] += v1.y; r[6] += v1.z; r[7] += v1.w;
      }
      float4* mo4 = (float4*)(mn + (size_t)b * MFLAT + dp0);
      mo4[0] = make_float4(r[0], r[1], r[2], r[3]);
      mo4[1] = make_float4(r[4], r[5], r[6], r[7]);
      unsigned short ph[8], pl[8];
      #pragma unroll
      for (int j = 0; j < 8; ++j) {
        ph[j] = f2bf(r[j]);
        pl[j] = f2bf(r[j] - bf2f(ph[j]));
      }
      size_t moff = (size_t)b * KTOT + IN_D + HID + dp0;
      *(short8v*)(snh + moff) = *(short8v*)ph;
      *(short8v*)(snl + moff) = *(short8v*)pl;

      if (t + 1 < SEQ) {
        const float* xn = x + ((size_t)b * SEQ + t + 1) * IN_D;
        for (int k = tid; k < IN_D; k += 256) {
          float xv = xn[k];
          unsigned short hi = f2bf(xv);
          snh[(size_t)b * KTOT + k] = hi;
          snl[(size_t)b * KTOT + k] = f2bf(xv - bf2f(hi));
        }
      }
      __syncthreads();
      grid_barrier(barArr, barGo, ++ep);
    }
  }
}

// ---------------- launch ----------------
extern "C" void kernel_launch(void* const* d_in, const int* in_sizes, int n_in,
                              void* d_out, int out_size, void* d_ws, size_t ws_size,
                              hipStream_t stream) {
  const float* x  = (const float*)d_in[0];
  const float* Ex = (const float*)d_in[1];
  const float* Eh = (const float*)d_in[2];
  const float* Em = (const float*)d_in[3];
  const float* Wx = (const float*)d_in[4];
  const float* Wh = (const float*)d_in[5];
  const float* Wm = (const float*)d_in[6];
  float* out = (float*)d_out;
  float* ws = (float*)d_ws;

  float* dAnat = ws;                         // 65536 f
  float* dAdT  = dAnat + 65536;              // 65536 f
  float* dBd   = dAdT + 65536;               // 512 f
  float* dWmB  = dBd + 512;                  // 8192 f
  unsigned short* dGhi = (unsigned short*)(dWmB + 8192);      // 1024*3584 ush
  unsigned short* dGlo = dGhi + (size_t)HID * KTOT;
  unsigned short* sh0  = dGlo + (size_t)HID * KTOT;           // 64*3584 ush each
  unsigned short* sh1  = sh0 + (size_t)B_SZ * KTOT;
  unsigned short* sl0  = sh1 + (size_t)B_SZ * KTOT;
  unsigned short* sl1  = sl0 + (size_t)B_SZ * KTOT;
  float* hfp0 = (float*)(sl1 + (size_t)B_SZ * KTOT);
  float* hfp1 = hfp0 + B_SZ * HID;
  float* mfp0 = hfp1 + B_SZ * HID;
  float* mfp1 = mfp0 + B_SZ * MFLAT;
  unsigned* barArr  = (unsigned*)(mfp1 + B_SZ * MFLAT);       // NBLK*16
  unsigned* barGo   = barArr + NBLK * BAR_STRIDE;             // 16

  static float h_AdT[ORD * ORD];
  static float h_Anat[ORD * ORD];
  static float h_Bd[ORD];
  compute_AB_host(h_AdT, h_Anat, h_Bd);
  hipMemcpyAsync(dAdT,  h_AdT,  sizeof(h_AdT),  hipMemcpyHostToDevice, stream);
  hipMemcpyAsync(dAnat, h_Anat, sizeof(h_Anat), hipMemcpyHostToDevice, stream);
  hipMemcpyAsync(dBd,   h_Bd,   sizeof(h_Bd),   hipMemcpyHostToDevice, stream);

  hipMemsetAsync(sh0, 0, (size_t)B_SZ * KTOT * sizeof(unsigned short), stream);
  hipMemsetAsync(sl0, 0, (size_t)B_SZ * KTOT * sizeof(unsigned short), stream);
  hipMemsetAsync(hfp0, 0, (size_t)B_SZ * HID * sizeof(float), stream);
  hipMemsetAsync(mfp0, 0, (size_t)B_SZ * MFLAT * sizeof(float), stream);
  hipMemsetAsync(barArr, 0,
                 (size_t)(NBLK * BAR_STRIDE + BAR_STRIDE) * sizeof(unsigned), stream);

  k_wmb<<<dim3(HID), dim3(256), 0, stream>>>(Wm, dBd, dWmB);
  k_gcat<<<dim3(HID), dim3(256), 0, stream>>>(Wx, Wh, Wm, Ex, Eh, Em, dAnat, dWmB, dGhi, dGlo);

  k_persist<<<dim3(NBLK), dim3(256), 0, stream>>>(
      x, Ex, Eh, Em, dGhi, dGlo, dAdT, dBd, sh0, sh1, sl0, sl1,
      hfp0, hfp1, mfp0, mfp1, out, barArr, barGo);
}

// Round 13
// 17923.117 us; speedup vs baseline: 8.5221x; 3.3189x over previous
//
#include <hip/hip_runtime.h>
#include <cmath>
#include <vector>

#define B_SZ 64
#define SEQ 512
#define IN_D 512
#define HID 1024
#define MEM_DIM 8
#define ORD 256
#define MFLAT 2048
#define KTOT 3584            // x(512) | h(1024) | m(2048)
#define NH 128               // H-role blocks: 8 slices x 4 isub x 4 bq
#define NM 64                // M-role blocks
#define NBLK (NH + NM)       // 192
#define BAR_STRIDE 16        // u32 stride per slot (64B)
#define RING 64              // state ring depth (reuse distance 64 > inv gap 32)
#define SSLOT ((size_t)B_SZ * KTOT)   // ushorts per ring slot (one plane)

typedef __attribute__((ext_vector_type(8))) short short8v;
typedef __attribute__((ext_vector_type(4))) float f32x4;
typedef unsigned long long u64;

// RNE float->bf16
__device__ __host__ inline unsigned short f2bf(float f) {
  union { float f; unsigned u; } v; v.f = f;
  unsigned r = v.u + 0x7FFF + ((v.u >> 16) & 1);
  return (unsigned short)(r >> 16);
}
__device__ __host__ inline float bf2f(unsigned short h) {
  union { unsigned u; float f; } v; v.u = ((unsigned)h) << 16;
  return v.f;
}

// ---------------- host-side expm (double, scaling & squaring) ----------------
static void matmul_d(const double* A, const double* B, double* C, int n) {
  for (int i = 0; i < n; ++i) {
    double* Ci = C + (size_t)i * n;
    for (int j = 0; j < n; ++j) Ci[j] = 0.0;
    const double* Ai = A + (size_t)i * n;
    for (int k = 0; k < n; ++k) {
      double a = Ai[k];
      const double* Bk = B + (size_t)k * n;
      for (int j = 0; j < n; ++j) Ci[j] += a * Bk[j];
    }
  }
}

static void compute_AB_host(float* AdT, float* Anat, float* Bd) {
  const int q = ORD, n = ORD + 1;
  const double theta = 512.0;
  std::vector<double> M((size_t)n * n, 0.0);
  for (int i = 0; i < q; ++i) {
    double r = (2.0 * i + 1.0) / theta;
    for (int j = 0; j < q; ++j) {
      double v = (i < j) ? -1.0 : ((((i - j) % 2) == 1) ? 1.0 : -1.0);
      M[(size_t)i * n + j] = v * r;
    }
    M[(size_t)i * n + q] = (((i % 2) == 0) ? 1.0 : -1.0) * r;
  }
  double norm = 0.0;
  for (int j = 0; j < n; ++j) {
    double s = 0.0;
    for (int i = 0; i < n; ++i) s += fabs(M[(size_t)i * n + j]);
    if (s > norm) norm = s;
  }
  int s = 0;
  while (norm > 0.25) { norm *= 0.5; ++s; }
  double sc = ldexp(1.0, -s);
  for (size_t i = 0; i < M.size(); ++i) M[i] *= sc;
  std::vector<double> E((size_t)n * n, 0.0), P = M, T((size_t)n * n);
  for (int i = 0; i < n; ++i) E[(size_t)i * n + i] = 1.0;
  for (size_t i = 0; i < M.size(); ++i) E[i] += M[i];
  for (int k = 2; k <= 30; ++k) {
    matmul_d(P.data(), M.data(), T.data(), n);
    double inv = 1.0 / (double)k, mx = 0.0;
    for (size_t i = 0; i < T.size(); ++i) {
      T[i] *= inv;
      double a = fabs(T[i]);
      if (a > mx) mx = a;
    }
    P.swap(T);
    for (size_t i = 0; i < M.size(); ++i) E[i] += P[i];
    if (mx < 1e-19) break;
  }
  for (int it = 0; it < s; ++it) {
    matmul_d(E.data(), E.data(), T.data(), n);
    E.swap(T);
  }
  for (int p = 0; p < q; ++p) {
    for (int o = 0; o < q; ++o) {
      float v = (float)E[(size_t)p * n + o];
      AdT[(size_t)o * q + p] = v;
      Anat[(size_t)p * q + o] = v;
    }
    Bd[p] = (float)E[(size_t)p * n + q];
  }
}

// ---------------- precompute kernels ----------------
__global__ __launch_bounds__(256) void k_wmb(const float* __restrict__ Wm,
                                             const float* __restrict__ Bd,
                                             float* __restrict__ WmB) {
  int i = blockIdx.x;
  int d = threadIdx.x >> 5, l = threadIdx.x & 31;
  const float* wr = Wm + (size_t)i * MFLAT + d * ORD;
  float acc = 0.f;
  #pragma unroll
  for (int j = 0; j < 8; ++j) { int p = l + 32 * j; acc += wr[p] * Bd[p]; }
  for (int off = 16; off; off >>= 1) acc += __shfl_xor(acc, off);
  if (l == 0) WmB[i * 8 + d] = acc;
}

__global__ __launch_bounds__(256) void k_gcat(
    const float* __restrict__ Wx, const float* __restrict__ Wh,
    const float* __restrict__ Wm, const float* __restrict__ Ex,
    const float* __restrict__ Eh, const float* __restrict__ Em,
    const float* __restrict__ Anat, const float* __restrict__ WmB,
    unsigned short* __restrict__ Ghi, unsigned short* __restrict__ Glo) {
  __shared__ float wm[MFLAT];
  __shared__ float wb[8];
  int i = blockIdx.x, tid = threadIdx.x;
  for (int k = tid; k < MFLAT; k += 256) wm[k] = Wm[(size_t)i * MFLAT + k];
  if (tid < 8) wb[tid] = WmB[i * 8 + tid];
  __syncthreads();
  unsigned short* grh = Ghi + (size_t)i * KTOT;
  unsigned short* grl = Glo + (size_t)i * KTOT;
  for (int c = tid; c < KTOT; c += 256) {
    float v;
    if (c < IN_D) {
      v = Wx[(size_t)i * IN_D + c];
      #pragma unroll
      for (int d = 0; d < 8; ++d) v += wb[d] * Ex[(size_t)d * IN_D + c];
    } else if (c < IN_D + HID) {
      int j = c - IN_D;
      v = Wh[(size_t)i * HID + j];
      #pragma unroll
      for (int d = 0; d < 8; ++d) v += wb[d] * Eh[(size_t)d * HID + j];
    } else {
      int cm = c - IN_D - HID;        // (d,o)
      int dd = cm >> 8, o = cm & 255;
      v = 0.f;
      const float* wmd = wm + dd * ORD;
      for (int p = 0; p < ORD; ++p) v += wmd[p] * Anat[(size_t)p * ORD + o];
      #pragma unroll
      for (int d = 0; d < 8; ++d) v += wb[d] * Em[(size_t)d * MFLAT + cm];
    }
    unsigned short hi = f2bf(v);
    grh[c] = hi;
    grl[c] = f2bf(v - bf2f(hi));
  }
}

// ---------------- tree barrier: RELEASE flags (wbl2, no inv) + PERIODIC acquire ----------------
// Release flag stores push producers' plain stores to LLC each step. The acquire
// fence (full per-XCD L2 invalidate) runs only when inv==true (every 32 steps):
// ring reuse distance is 64 > 32, so no address can be re-read through a stale
// L2 line. G/AdT stay L2-resident between invs.
__device__ inline void grid_barrier(unsigned* __restrict__ arr,
                                    unsigned* __restrict__ go, unsigned ep,
                                    bool inv) {
  __syncthreads();
  if (blockIdx.x == 0) {
    int tid = threadIdx.x;
    if (tid > 0 && tid < NBLK) {
      while (__hip_atomic_load(&arr[tid * BAR_STRIDE], __ATOMIC_RELAXED,
                               __HIP_MEMORY_SCOPE_AGENT) < ep)
        __builtin_amdgcn_s_sleep(1);
    }
    __syncthreads();
    if (tid == 0)
      __hip_atomic_store(go, ep, __ATOMIC_RELEASE, __HIP_MEMORY_SCOPE_AGENT);
  } else {
    if (threadIdx.x == 0) {
      __hip_atomic_store(&arr[blockIdx.x * BAR_STRIDE], ep, __ATOMIC_RELEASE,
                         __HIP_MEMORY_SCOPE_AGENT);
      while (__hip_atomic_load(go, __ATOMIC_RELAXED,
                               __HIP_MEMORY_SCOPE_AGENT) < ep)
        __builtin_amdgcn_s_sleep(1);
    }
  }
  if (inv && threadIdx.x == 0)
    __builtin_amdgcn_fence(__ATOMIC_ACQUIRE, "agent");
  __syncthreads();
}

// ---------------- persistent kernel ----------------
// H blocks [0,128): blk = s + 8*(isub + 4*bq); slice s -> XCD s (G L2-resident).
// Tile 16b x 32i; waves (tw = i-half, kh = K-half); inner loop = r12-proven.
// State mirrors live in a RING (slot = t & 63): plain cached loads/stores.
// M blocks [128,192): batch b; h rebuilt from ring mirrors; fp32 m private.
__global__ __launch_bounds__(256) void k_persist(
    const float* __restrict__ x, const float* __restrict__ Ex,
    const float* __restrict__ Eh, const float* __restrict__ Em,
    const unsigned short* __restrict__ Ghi, const unsigned short* __restrict__ Glo,
    const float* __restrict__ AdT, const float* __restrict__ Bd,
    unsigned short* __restrict__ shR, unsigned short* __restrict__ slR,
    float* __restrict__ mfp0, float* __restrict__ mfp1,
    float* __restrict__ out, unsigned* __restrict__ barArr,
    unsigned* __restrict__ barGo) {
  int tid = threadIdx.x;
  unsigned ep = 0;

  if (blockIdx.x < NH) {
    // ================= H role =================
    __shared__ float hx[2][64][4];
    int s = blockIdx.x & 7, sub = blockIdx.x >> 3;
    int isub = sub & 3, bq = sub >> 2;
    int w = tid >> 6, lane = tid & 63;
    int tw = w & 1, kh = w >> 1;
    int b0 = bq * 16;
    int i0 = s * 128 + isub * 32 + tw * 16;
    size_t aoff = (size_t)(b0 + (lane & 15)) * KTOT + (lane >> 4) * 8;
    const unsigned short* bh_ = Ghi + (size_t)(i0 + (lane & 15)) * KTOT + (lane >> 4) * 8;
    const unsigned short* bl_ = Glo + (size_t)(i0 + (lane & 15)) * KTOT + (lane >> 4) * 8;

    grid_barrier(barArr, barGo, ++ep, false);   // wait x_0 seed

    for (int t = 0; t < SEQ; ++t) {
      const unsigned short* ah_ = shR + (size_t)(t & (RING - 1)) * SSLOT + aoff;
      const unsigned short* al_ = slR + (size_t)(t & (RING - 1)) * SSLOT + aoff;
      unsigned short* snh = shR + (size_t)((t + 1) & (RING - 1)) * SSLOT;
      unsigned short* snl = slR + (size_t)((t + 1) & (RING - 1)) * SSLOT;

      f32x4 ahh = {0.f,0.f,0.f,0.f}, alh = {0.f,0.f,0.f,0.f}, ahl = {0.f,0.f,0.f,0.f};
      int kbase = kh * 1792;
      #pragma unroll 4
      for (int kk = 0; kk < 56; ++kk) {
        int k = kbase + kk * 32;
        short8v avh = *(const short8v*)(ah_ + k);
        short8v avl = *(const short8v*)(al_ + k);
        short8v bvh = *(const short8v*)(bh_ + k);
        short8v bvl = *(const short8v*)(bl_ + k);
        ahh = __builtin_amdgcn_mfma_f32_16x16x32_bf16(avh, bvh, ahh, 0, 0, 0);
        alh = __builtin_amdgcn_mfma_f32_16x16x32_bf16(avl, bvh, alh, 0, 0, 0);
        ahl = __builtin_amdgcn_mfma_f32_16x16x32_bf16(avh, bvl, ahl, 0, 0, 0);
      }
      f32x4 acc = ahh + alh + ahl;
      if (kh == 1) {
        *(f32x4*)&hx[tw][lane][0] = acc;
      }
      __syncthreads();
      if (kh == 0) {
        f32x4 o4 = *(const f32x4*)&hx[tw][lane][0];
        #pragma unroll
        for (int r = 0; r < 4; ++r) {
          float v = acc[r] + o4[r];
          float hv = tanhf(v);
          int b = b0 + (lane >> 4) * 4 + r;
          int i = i0 + (lane & 15);
          unsigned short hi = f2bf(hv);
          snh[(size_t)b * KTOT + IN_D + i] = hi;
          snl[(size_t)b * KTOT + IN_D + i] = f2bf(hv - bf2f(hi));
          __builtin_nontemporal_store(hv, &out[((size_t)b * SEQ + t) * HID + i]);
        }
      }
      grid_barrier(barArr, barGo, ++ep, (t & 31) == 31);
    }
  } else {
    // ================= M role =================
    __shared__ float sst[KTOT];
    __shared__ float mpart[4][MFLAT];
    __shared__ float ush[8];
    int b = blockIdx.x - NH;
    int du = tid >> 5, lu = tid & 31;
    const float* exr = Ex + (size_t)du * IN_D;
    const float* ehr = Eh + (size_t)du * HID;
    const float* emr = Em + (size_t)du * MFLAT;
    int os = tid >> 6;
    int p0 = (tid & 63) * 4;
    int dp0 = tid * 8;
    int dr = tid >> 5;
    float bdv[8];
    #pragma unroll
    for (int j = 0; j < 8; ++j) bdv[j] = Bd[(dp0 & 255) + j];

    // seed x_0 hi/lo into ring slot 0 (h/m of slot 0 are zeroed by host memset)
    {
      const float* xr = x + (size_t)b * SEQ * IN_D;
      for (int k = tid; k < IN_D; k += 256) {
        float xv = xr[k];
        unsigned short hi = f2bf(xv);
        shR[(size_t)b * KTOT + k] = hi;
        slR[(size_t)b * KTOT + k] = f2bf(xv - bf2f(hi));
      }
    }
    grid_barrier(barArr, barGo, ++ep, false);

    for (int t = 0; t < SEQ; ++t) {
      const unsigned short* scH = shR + (size_t)(t & (RING - 1)) * SSLOT;
      const unsigned short* scL = slR + (size_t)(t & (RING - 1)) * SSLOT;
      unsigned short* snh = shR + (size_t)((t + 1) & (RING - 1)) * SSLOT;
      unsigned short* snl = slR + (size_t)((t + 1) & (RING - 1)) * SSLOT;
      const float* mc = (t & 1) ? mfp1 : mfp0;
      float* mn = (t & 1) ? mfp0 : mfp1;

      // stage [x_t | h | m] fp32 to LDS
      const float* xrow = x + ((size_t)b * SEQ + t) * IN_D;
      #pragma unroll
      for (int j = 0; j < 2; ++j) {                 // x: plain cached input
        int k = tid + 256 * j;
        sst[k] = xrow[k];
      }
      {                                             // h: from ring mirrors (plain)
        int k4 = tid * 4;
        const unsigned short* hh = scH + (size_t)b * KTOT + IN_D + k4;
        const unsigned short* hl = scL + (size_t)b * KTOT + IN_D + k4;
        #pragma unroll
        for (int j = 0; j < 4; ++j)
          sst[IN_D + k4 + j] = bf2f(hh[j]) + bf2f(hl[j]);
      }
      {                                             // m: private fp32 master
        const float4* mc4 = (const float4*)(mc + (size_t)b * MFLAT);
        float4* sst4 = (float4*)(sst + IN_D + HID);
        #pragma unroll
        for (int j = 0; j < 2; ++j) {
          int g = tid + 256 * j;
          sst4[g] = mc4[g];
        }
      }
      __syncthreads();

      float ua = 0.f;
      #pragma unroll 4
      for (int j = 0; j < 16; ++j) { int k = lu + 32 * j; ua += exr[k] * sst[k]; }
      #pragma unroll 4
      for (int j = 0; j < 32; ++j) { int k = lu + 32 * j; ua += ehr[k] * sst[IN_D + k]; }
      #pragma unroll 4
      for (int j = 0; j < 64; ++j) { int k = lu + 32 * j; ua += emr[k] * sst[IN_D + HID + k]; }
      #pragma unroll
      for (int off = 16; off; off >>= 1) ua += __shfl_xor(ua, off);
      if (lu == 0) ush[du] = ua;
      __syncthreads();

      float acc[8][4];
      #pragma unroll
      for (int d = 0; d < 8; ++d)
        acc[d][0] = acc[d][1] = acc[d][2] = acc[d][3] = 0.f;
      const float* mbase = sst + IN_D + HID;
      #pragma unroll 4
      for (int oo = 0; oo < 64; ++oo) {
        int o = os * 64 + oo;
        float4 qv = *(const float4*)(AdT + (size_t)o * ORD + p0);
        #pragma unroll
        for (int d = 0; d < 8; ++d) {
          float mv = mbase[d * ORD + o];
          acc[d][0] = fmaf(qv.x, mv, acc[d][0]);
          acc[d][1] = fmaf(qv.y, mv, acc[d][1]);
          acc[d][2] = fmaf(qv.z, mv, acc[d][2]);
          acc[d][3] = fmaf(qv.w, mv, acc[d][3]);
        }
      }
      #pragma unroll
      for (int d = 0; d < 8; ++d)
        *(float4*)&mpart[os][d * ORD + p0] =
            make_float4(acc[d][0], acc[d][1], acc[d][2], acc[d][3]);
      __syncthreads();

      float r[8];
      float uv = ush[dr];
      #pragma unroll
      for (int j = 0; j < 8; ++j) r[j] = bdv[j] * uv;
      #pragma unroll
      for (int sI = 0; sI < 4; ++sI) {
        float4 v0 = *(const float4*)&mpart[sI][dp0];
        float4 v1 = *(const float4*)&mpart[sI][dp0 + 4];
        r[0] += v0.x; r[1] += v0.y; r[2] += v0.z; r[3] += v0.w;
        r[4] += v1.x; r[5] += v1.y; r[6] += v1.z; r[7] += v1.w;
      }
      float4* mo4 = (float4*)(mn + (size_t)b * MFLAT + dp0);
      mo4[0] = make_float4(r[0], r[1], r[2], r[3]);
      mo4[1] = make_float4(r[4], r[5], r[6], r[7]);
      unsigned short ph[8], pl[8];
      #pragma unroll
      for (int j = 0; j < 8; ++j) {
        ph[j] = f2bf(r[j]);
        pl[j] = f2bf(r[j] - bf2f(ph[j]));
      }
      size_t moff = (size_t)b * KTOT + IN_D + HID + dp0;
      *(short8v*)(snh + moff) = *(short8v*)ph;
      *(short8v*)(snl + moff) = *(short8v*)pl;

      if (t + 1 < SEQ) {
        const float* xn = x + ((size_t)b * SEQ + t + 1) * IN_D;
        for (int k = tid; k < IN_D; k += 256) {
          float xv = xn[k];
          unsigned short hi = f2bf(xv);
          snh[(size_t)b * KTOT + k] = hi;
          snl[(size_t)b * KTOT + k] = f2bf(xv - bf2f(hi));
        }
      }
      __syncthreads();
      grid_barrier(barArr, barGo, ++ep, (t & 31) == 31);
    }
  }
}

// ---------------- launch ----------------
extern "C" void kernel_launch(void* const* d_in, const int* in_sizes, int n_in,
                              void* d_out, int out_size, void* d_ws, size_t ws_size,
                              hipStream_t stream) {
  const float* x  = (const float*)d_in[0];
  const float* Ex = (const float*)d_in[1];
  const float* Eh = (const float*)d_in[2];
  const float* Em = (const float*)d_in[3];
  const float* Wx = (const float*)d_in[4];
  const float* Wh = (const float*)d_in[5];
  const float* Wm = (const float*)d_in[6];
  float* out = (float*)d_out;
  float* ws = (float*)d_ws;

  float* dAnat = ws;                         // 65536 f
  float* dAdT  = dAnat + 65536;              // 65536 f
  float* dBd   = dAdT + 65536;               // 512 f
  float* dWmB  = dBd + 512;                  // 8192 f
  unsigned short* dGhi = (unsigned short*)(dWmB + 8192);      // HID*KTOT ush
  unsigned short* dGlo = dGhi + (size_t)HID * KTOT;
  unsigned short* shR  = dGlo + (size_t)HID * KTOT;           // RING*SSLOT ush
  unsigned short* slR  = shR + (size_t)RING * SSLOT;
  float* mfp0 = (float*)(slR + (size_t)RING * SSLOT);
  float* mfp1 = mfp0 + B_SZ * MFLAT;
  unsigned* barArr  = (unsigned*)(mfp1 + B_SZ * MFLAT);       // NBLK*16
  unsigned* barGo   = barArr + NBLK * BAR_STRIDE;             // 16

  static float h_AdT[ORD * ORD];
  static float h_Anat[ORD * ORD];
  static float h_Bd[ORD];
  compute_AB_host(h_AdT, h_Anat, h_Bd);
  hipMemcpyAsync(dAdT,  h_AdT,  sizeof(h_AdT),  hipMemcpyHostToDevice, stream);
  hipMemcpyAsync(dAnat, h_Anat, sizeof(h_Anat), hipMemcpyHostToDevice, stream);
  hipMemcpyAsync(dBd,   h_Bd,   sizeof(h_Bd),   hipMemcpyHostToDevice, stream);

  // zero ring slot 0 (h,m regions must start at 0; x seeded by M pre-loop)
  hipMemsetAsync(shR, 0, SSLOT * sizeof(unsigned short), stream);
  hipMemsetAsync(slR, 0, SSLOT * sizeof(unsigned short), stream);
  hipMemsetAsync(mfp0, 0, (size_t)B_SZ * MFLAT * sizeof(float), stream);
  hipMemsetAsync(barArr, 0,
                 (size_t)(NBLK * BAR_STRIDE + BAR_STRIDE) * sizeof(unsigned), stream);

  k_wmb<<<dim3(HID), dim3(256), 0, stream>>>(Wm, dBd, dWmB);
  k_gcat<<<dim3(HID), dim3(256), 0, stream>>>(Wx, Wh, Wm, Ex, Eh, Em, dAnat, dWmB, dGhi, dGlo);

  k_persist<<<dim3(NBLK), dim3(256), 0, stream>>>(
      x, Ex, Eh, Em, dGhi, dGlo, dAdT, dBd, shR, slR,
      mfp0, mfp1, out, barArr, barGo);
}